// Round 20
// baseline (773.265 us; speedup 1.0000x reference)
//
#include <hip/hip_runtime.h>
#include <math.h>

#define Lnum 8
#define Bn 4
#define Tn 2048
#define Dn 256
#define Sn 512
#define BT (Bn*Tn)      // 8192
#define ZW 1536         // zb row: [bx_r(512) | bx_i(512) | gate(512)]
#define WARM 24         // scan warmup; carry bound 0.7625^24 = 1.5e-3
#define TC 32           // scan chunk

typedef __attribute__((ext_vector_type(8))) short bf16x8;
typedef __attribute__((ext_vector_type(4))) float f32x4;

__device__ __forceinline__ ushort f2bf(float f) {
    union { float f; unsigned u; } v; v.f = f;
    unsigned r = v.u + 0x7fffu + ((v.u >> 16) & 1u);   // RNE
    return (ushort)(r >> 16);
}
__device__ __forceinline__ float bf2f(ushort u) {
    union { unsigned u; float f; } v; v.u = ((unsigned)u) << 16; return v.f;
}

// direct global->LDS async copy, 16B/lane (dest = wave-uniform base + lane*16)
__device__ __forceinline__ void gload16(const void* g, void* l) {
    using u32 = unsigned int;
    auto gp = (const __attribute__((address_space(1))) u32*)(uintptr_t)g;
    auto lp = (__attribute__((address_space(3))) u32*)(uintptr_t)l;
    __builtin_amdgcn_global_load_lds(gp, lp, 16, 0, 0);
}

// ---------------- phase-preserving RMS norm: h[BT,D,2] -> xnp (fragment-packed bf16)
// XCD-aligned: block v=bid&7 handles bt in [1024v, 1024v+1024).
__global__ __launch_bounds__(256)
void norm_kernel(const float* __restrict__ h, const float* __restrict__ g,
                 ushort* __restrict__ xnp)
{
    const int bt = (blockIdx.x & 7)*1024 + (blockIdx.x >> 3);
    const int d  = threadIdx.x;
    const float2 v = reinterpret_cast<const float2*>(h)[(size_t)bt*Dn + d];
    float sum = v.x*v.x + v.y*v.y;
    #pragma unroll
    for (int o = 32; o > 0; o >>= 1) sum += __shfl_down(sum, o);
    __shared__ float ws4[4];
    if ((threadIdx.x & 63) == 0) ws4[threadIdx.x >> 6] = sum;
    __syncthreads();
    const float tot = ws4[0] + ws4[1] + ws4[2] + ws4[3];
    const float rms = sqrtf(tot * (1.0f/Dn) + 1e-6f);
    const float scale = g[d] / rms;
    const int rowgrp = bt >> 4, rl = bt & 15;
    const int k1 = d, k2 = 256 + d;
    const size_t i1 = (((size_t)rowgrp*16 + (k1>>5))*64 + ((k1>>3)&3)*16 + rl)*8 + (k1&7);
    const size_t i2 = (((size_t)rowgrp*16 + (k2>>5))*64 + ((k2>>3)&3)*16 + rl)*8 + (k2&7);
    xnp[i1] = f2bf(v.x * scale);
    xnp[i2] = f2bf(v.y * scale);
}

// ---------------- final norm, fp32 interleaved output (same XCD-aligned decode)
__global__ __launch_bounds__(256)
void out_norm_kernel(const float* __restrict__ h, const float* __restrict__ g,
                     float* __restrict__ out)
{
    const int bt = (blockIdx.x & 7)*1024 + (blockIdx.x >> 3);
    const int d  = threadIdx.x;
    const float2 v = reinterpret_cast<const float2*>(h)[(size_t)bt*Dn + d];
    float sum = v.x*v.x + v.y*v.y;
    #pragma unroll
    for (int o = 32; o > 0; o >>= 1) sum += __shfl_down(sum, o);
    __shared__ float ws4[4];
    if ((threadIdx.x & 63) == 0) ws4[threadIdx.x >> 6] = sum;
    __syncthreads();
    const float tot = ws4[0] + ws4[1] + ws4[2] + ws4[3];
    const float rms = sqrtf(tot * (1.0f/Dn) + 1e-6f);
    const float scale = g[d] / rms;
    float2 o; o.x = v.x * scale; o.y = v.y * scale;
    reinterpret_cast<float2*>(out)[(size_t)bt*Dn + d] = o;
}

// ======== GEMM1: zb[8192,1536] = xn @ W1^T — 16-wave re-tile of the panel structure.
// Block: 96-col panel (96KB LDS, full K=512) x 512 rows; 16 waves x (32 rows x 96 cols).
// acc[2][6]=48 VGPR/wave, half the load chains per wave, 2x TLP (16 waves/CU).
// Grid 256 = 1 block/CU; XCD v owns rsplits {2v, 2v+1}. Memory behavior identical to R18.
__global__ __launch_bounds__(1024, 4)
void gemm1_kernel(const ushort* __restrict__ xnp, const ushort* __restrict__ W1f,
                  ushort* __restrict__ zb, const float* __restrict__ bias)
{
    __shared__ ushort Blds[49152];   // 96 KB: [n(6)][ks(16)][lane(64)][e(8)]
    const int tid = threadIdx.x, lane = tid & 63, wid = tid >> 6;   // wid 0..15
    const int xcd = blockIdx.x & 7, j0 = blockIdx.x >> 3;   // j0 0..31
    const int rsplit = xcd*2 + (j0 & 1);   // 0..15 (512-row splits)
    const int panel  = j0 >> 1;            // 0..15 (96-col panels)

    // stage B panel: 96 KB contiguous, 6 rounds of 16KB (1024 lanes x 16B)
    const char* src = (const char*)(W1f + (size_t)panel*49152);
    #pragma unroll
    for (int r = 0; r < 6; ++r)
        gload16(src + r*16384 + tid*16, (char*)Blds + r*16384 + wid*1024);
    asm volatile("s_waitcnt vmcnt(0)" ::: "memory");
    __syncthreads();

    const int rgbase = rsplit*32 + wid*2;   // 2 rowgrps (32 rows) per wave
    const ushort* pa = xnp + (size_t)rgbase*16*512 + lane*8;

    f32x4 acc[2][6] = {};
    bf16x8 AS[4][2], BS[2][6];

#define LDA1(s, ks) { _Pragma("unroll") for (int m = 0; m < 2; ++m) \
    AS[s][m] = *(const bf16x8*)(pa + ((size_t)m*16 + (ks))*512); }
#define LDB1(s, ks) { _Pragma("unroll") for (int n = 0; n < 6; ++n) \
    BS[s][n] = *(const bf16x8*)(Blds + ((n)*16 + (ks))*512 + lane*8); }

    LDA1(0,0); LDA1(1,1); LDA1(2,2); LDA1(3,3);
    LDB1(0,0); LDB1(1,1);
    __builtin_amdgcn_sched_barrier(0);
    #pragma unroll
    for (int ks = 0; ks < 16; ++ks) {
        __builtin_amdgcn_s_setprio(1);
        #pragma unroll
        for (int n = 0; n < 6; ++n)
            #pragma unroll
            for (int m = 0; m < 2; ++m)
                acc[m][n] = __builtin_amdgcn_mfma_f32_16x16x32_bf16(AS[ks & 3][m], BS[ks & 1][n], acc[m][n], 0, 0, 0);
        __builtin_amdgcn_s_setprio(0);
        if (ks + 4 < 16) LDA1((ks & 3), ks + 4);
        if (ks + 2 < 16) LDB1((ks & 1), ks + 2);
        __builtin_amdgcn_sched_barrier(0);
    }
#undef LDA1
#undef LDB1

    const int rl = lane & 15, rbase = (lane >> 4)*4;
    #pragma unroll
    for (int m = 0; m < 2; ++m) {
        #pragma unroll
        for (int n = 0; n < 6; ++n) {
            const int gcol = panel*96 + n*16 + rl;
            const float badd = bias[gcol];
            const bool sg = (gcol >= 1024);
            #pragma unroll
            for (int r = 0; r < 4; ++r) {
                const int grow = rsplit*512 + wid*32 + m*16 + rbase + r;
                float v = acc[m][n][r] + badd;
                if (sg) v = 1.0f/(1.0f + __expf(-v));
                zb[(size_t)grow*ZW + gcol] = f2bf(v);
            }
        }
    }
}

// ======== scan (warmup, 1 pass): zb -> hsp fragment-packed (XCD-aligned, R18 verbatim)
__global__ __launch_bounds__(256)
void scan_kernel(const ushort* __restrict__ zb, const float* __restrict__ theta,
                 const float* __restrict__ dp, const float* __restrict__ h0,
                 ushort* __restrict__ hsp)
{
    const int v = blockIdx.x & 7, i = blockIdx.x >> 3;
    const int b = v >> 1;
    const int c = (v & 1)*32 + i;
    const int s = blockIdx.z*256 + threadIdx.x;
    const int t0 = c*TC;
    const float th = theta[s], ct = cosf(th), st = sinf(th);
    const float damp = 0.5f + 0.5f/(1.0f + __expf(-dp[s]));
    const int wstart = (t0 >= WARM) ? (t0 - WARM) : 0;
    float hr = 0.f, hi = 0.f;
    if (wstart == 0) {
        hr = h0[((size_t)b*Sn + s)*2];
        hi = h0[((size_t)b*Sn + s)*2 + 1];
    }
    const ushort* row = zb + (size_t)(b*Tn + wstart)*ZW;
    for (int t = wstart; t < t0; ++t, row += ZW) {
        const float br = bf2f(row[s]), bi = bf2f(row[512+s]), g = bf2f(row[1024+s]);
        const float mm = (1.0f - g)*damp;
        const float mc = mm*ct, ms = mm*st;
        const float rr = mc*hr - ms*hi, ri = ms*hr + mc*hi;
        hr = g*br + rr;  hi = g*bi + ri;
    }
    const int rgb = (b*Tn + t0) >> 4;
    const int kg16 = ((s >> 3) & 3)*16;
    const int e = s & 7;
    const int srow = (s >> 5)*512 + e;
    #pragma unroll
    for (int t = 0; t < TC; ++t, row += ZW) {
        const float br = bf2f(row[s]), bi = bf2f(row[512+s]), g = bf2f(row[1024+s]);
        const float mm = (1.0f - g)*damp;
        const float mc = mm*ct, ms = mm*st;
        const float rr = mc*hr - ms*hi, ri = ms*hr + mc*hi;
        hr = g*br + rr;  hi = g*bi + ri;
        const size_t ro = ((size_t)(rgb + (t >> 4))*32)*512 + srow + (kg16 + (t & 15))*8;
        hsp[ro]           = f2bf(hr);
        hsp[ro + 16*512]  = f2bf(hi);
    }
}

// ======== GEMM2 (B-panel in LDS, pinned reg pipeline): y = [hs|xn] @ W2^T (K=1536),
// interleaved (yr,yi) cols, fused residual h += 0.1*((1+yr)*y).  (R18 verbatim)
__global__ __launch_bounds__(512, 2)
void gemm2_kernel(const ushort* __restrict__ hsp, const ushort* __restrict__ xnp,
                  const ushort* __restrict__ W2f, float* __restrict__ h)
{
    __shared__ ushort Blds[49152];   // 96 KB: [n(2)][ks(48)][lane(64)][e(8)]
    const int tid = threadIdx.x, lane = tid & 63, wid = tid >> 6;
    const int xcd = blockIdx.x & 7, j = blockIdx.x >> 3;
    const int rsplit = xcd*2 + (j & 1);
    const int panel  = j >> 1;

    const char* src = (const char*)(W2f + (size_t)panel*49152);
    #pragma unroll
    for (int r = 0; r < 12; ++r)
        gload16(src + r*8192 + tid*16, (char*)Blds + r*8192 + wid*1024);
    asm volatile("s_waitcnt vmcnt(0)" ::: "memory");
    __syncthreads();

    const int rgbase = rsplit*32 + wid*4;
    const ushort* pa_h = hsp + (size_t)rgbase*32*512 + lane*8;
    const ushort* pa_x = xnp + (size_t)rgbase*16*512 + lane*8;

    f32x4 acc[4][2] = {};
    bf16x8 AS[8][4], BS[4][2];

#define LDA2(s, ks) { if ((ks) < 32) { \
    _Pragma("unroll") for (int m = 0; m < 4; ++m) \
        AS[s][m] = *(const bf16x8*)(pa_h + ((size_t)m*32 + (ks))*512); \
    } else { \
    _Pragma("unroll") for (int m = 0; m < 4; ++m) \
        AS[s][m] = *(const bf16x8*)(pa_x + ((size_t)m*16 + (ks) - 32)*512); } }
#define LDB2(s, ks) { _Pragma("unroll") for (int n = 0; n < 2; ++n) \
    BS[s][n] = *(const bf16x8*)(Blds + ((n)*48 + (ks))*512 + lane*8); }

    LDA2(0,0); LDA2(1,1); LDA2(2,2); LDA2(3,3);
    LDA2(4,4); LDA2(5,5); LDA2(6,6); LDA2(7,7);
    LDB2(0,0); LDB2(1,1); LDB2(2,2); LDB2(3,3);
    __builtin_amdgcn_sched_barrier(0);
    #pragma unroll
    for (int ks = 0; ks < 48; ++ks) {
        __builtin_amdgcn_s_setprio(1);
        #pragma unroll
        for (int n = 0; n < 2; ++n)
            #pragma unroll
            for (int m = 0; m < 4; ++m)
                acc[m][n] = __builtin_amdgcn_mfma_f32_16x16x32_bf16(AS[ks & 7][m], BS[ks & 3][n], acc[m][n], 0, 0, 0);
        __builtin_amdgcn_s_setprio(0);
        if (ks + 8 < 48) LDA2((ks & 7), ks + 8);
        if (ks + 4 < 48) LDB2((ks & 3), ks + 4);
        __builtin_amdgcn_sched_barrier(0);
    }
#undef LDA2
#undef LDB2

    const int rl = lane & 15, rbase = (lane >> 4)*4;
    #pragma unroll
    for (int m = 0; m < 4; ++m) {
        #pragma unroll
        for (int n = 0; n < 2; ++n) {
            const int gcol = panel*32 + n*16 + rl;   // parity(gcol)==parity(lane)
            #pragma unroll
            for (int r = 0; r < 4; ++r) {
                const int grow = rsplit*512 + wid*64 + m*16 + rbase + r;
                float v = acc[m][n][r];
                const float p = __shfl_xor(v, 1);
                const float yr = (gcol & 1) ? p : v;
                h[(size_t)grow*512 + gcol] += 0.1f*(yr*v + v);
            }
        }
    }
}

// ---------------- weight prep: W1f fragment-packed [colgrp(96)][ks(16)][lane][8]
__global__ __launch_bounds__(512)
void prep_w1(const float* __restrict__ Bwr, const float* __restrict__ Bwi,
             const float* __restrict__ Gw, ushort* __restrict__ W1f)
{
    const int l = blockIdx.y;
    const int bx = blockIdx.x;          // colgrp*16 + ks
    const int lane = threadIdx.x >> 3, e = threadIdx.x & 7;
    const int n = (bx >> 4)*16 + (lane & 15);
    const int k = (bx & 15)*32 + (lane >> 4)*8 + e;
    const float* bwr = Bwr + (size_t)l*Dn*Sn;
    const float* bwi = Bwi + (size_t)l*Dn*Sn;
    const float* gw  = Gw  + (size_t)l*2*Dn*Sn;
    float v;
    if (n < 512)        { const int s = n;      v = (k < 256) ? bwr[k*Sn + s] : -bwi[(k-256)*Sn + s]; }
    else if (n < 1024)  { const int s = n-512;  v = (k < 256) ? bwi[k*Sn + s] :  bwr[(k-256)*Sn + s]; }
    else                { const int s = n-1024; v = gw[(size_t)k*Sn + s]; }
    W1f[(size_t)l*1536*512 + (size_t)bx*512 + threadIdx.x] = f2bf(v);
}

// ---------------- weight prep: W2f fragment-packed [colgrp(32)][ks(48)][lane][8]
// K = [hs_r(512) | hs_i(512) | xr,xi(512)]; cols interleaved (yr,yi)
__global__ __launch_bounds__(512)
void prep_w2(const float* __restrict__ Cwr, const float* __restrict__ Cwi,
             const float* __restrict__ Dwr, const float* __restrict__ Dwi,
             ushort* __restrict__ W2f)
{
    const int l = blockIdx.y;
    const int bx = blockIdx.x;          // colgrp*48 + ks
    const int lane = threadIdx.x >> 3, e = threadIdx.x & 7;
    const int n = (bx / 48)*16 + (lane & 15);
    const int k = (bx % 48)*32 + (lane >> 4)*8 + e;
    const float* cwr = Cwr + (size_t)l*Sn*Dn;
    const float* cwi = Cwi + (size_t)l*Sn*Dn;
    const float* dwr = Dwr + (size_t)l*Dn*Dn;
    const float* dwi = Dwi + (size_t)l*Dn*Dn;
    const int d = n >> 1;
    const bool im = (n & 1);
    float v;
    if (k < 512)       v = im ? cwi[k*Dn + d]        :  cwr[k*Dn + d];
    else if (k < 1024) v = im ? cwr[(k-512)*Dn + d]  : -cwi[(k-512)*Dn + d];
    else if (k < 1280) v = im ? dwi[(k-1024)*Dn + d] :  dwr[(k-1024)*Dn + d];
    else               v = im ? dwr[(k-1280)*Dn + d] : -dwi[(k-1280)*Dn + d];
    W2f[(size_t)l*512*1536 + (size_t)bx*512 + threadIdx.x] = f2bf(v);
}

// ---------------- bias prep (1536 wide; gate bias in [1024,1536))
__global__ __launch_bounds__(256)
void prep_bias(const float* __restrict__ gb, float* __restrict__ biasf)
{
    const int l = blockIdx.y;
    const int n = blockIdx.x*256 + threadIdx.x;
    biasf[(size_t)l*1536 + n] = (n >= 1024) ? gb[(size_t)l*Sn + n - 1024] : 0.0f;
}

extern "C" void kernel_launch(void* const* d_in, const int* in_sizes, int n_in,
                              void* d_out, int out_size, void* d_ws, size_t ws_size,
                              hipStream_t stream)
{
    const float* x      = (const float*)d_in[0];
    const float* h0     = (const float*)d_in[1];
    const float* theta  = (const float*)d_in[2];
    const float* dp     = (const float*)d_in[3];
    const float* B_wr   = (const float*)d_in[4];
    const float* B_wi   = (const float*)d_in[5];
    const float* C_wr   = (const float*)d_in[6];
    const float* C_wi   = (const float*)d_in[7];
    const float* D_wr   = (const float*)d_in[8];
    const float* D_wi   = (const float*)d_in[9];
    const float* gate_w = (const float*)d_in[10];
    const float* gate_b = (const float*)d_in[11];
    const float* norm_g = (const float*)d_in[12];
    const float* out_g  = (const float*)d_in[13];
    float* out = (float*)d_out;

    char* w = (char*)d_ws;
    float*  h     = (float*)w;   w += (size_t)BT*512*4;         // 16 MB
    float*  biasf = (float*)w;   w += (size_t)8*1536*4;         // 48 KB
    ushort* zb    = (ushort*)w;  w += (size_t)BT*ZW*2;          // 24 MB
    ushort* xnp   = (ushort*)w;  w += (size_t)BT*512*2;         // 8 MB
    ushort* hsp   = (ushort*)w;  w += (size_t)BT*1024*2;        // 16 MB
    ushort* W1f   = (ushort*)w;  w += (size_t)Lnum*1536*512*2;  // 16 MB
    ushort* W2f   = (ushort*)w;  w += (size_t)Lnum*512*1536*2;  // 16 MB

    hipMemcpyAsync(h, x, sizeof(float)*(size_t)BT*Dn*2, hipMemcpyDeviceToDevice, stream);

    prep_w1<<<dim3(1536, Lnum), 512, 0, stream>>>(B_wr, B_wi, gate_w, W1f);
    prep_w2<<<dim3(1536, Lnum), 512, 0, stream>>>(C_wr, C_wi, D_wr, D_wi, W2f);
    prep_bias<<<dim3(6, Lnum), 256, 0, stream>>>(gate_b, biasf);

    for (int l = 0; l < Lnum; ++l) {
        norm_kernel<<<BT, 256, 0, stream>>>(h, norm_g + (size_t)l*Dn, xnp);

        gemm1_kernel<<<256, 1024, 0, stream>>>(xnp, W1f + (size_t)l*1536*512, zb,
                                               biasf + (size_t)l*1536);

        scan_kernel<<<dim3(256, 1, 2), 256, 0, stream>>>(zb, theta + (size_t)l*Sn,
                                                         dp + (size_t)l*Sn,
                                                         h0 + (size_t)l*Bn*Sn*2, hsp);

        gemm2_kernel<<<256, 512, 0, stream>>>(hsp, xnp, W2f + (size_t)l*512*1536, h);
    }

    out_norm_kernel<<<BT, 256, 0, stream>>>(h, out_g, out);
}

// Round 21
// 596.619 us; speedup vs baseline: 1.2961x; 1.2961x over previous
//
#include <hip/hip_runtime.h>
#include <math.h>

#define Lnum 8
#define Bn 4
#define Tn 2048
#define Dn 256
#define Sn 512
#define BT (Bn*Tn)      // 8192
#define ZW 1536         // zb row: [bx_r(512) | bx_i(512) | gate(512)]
#define WARM 32         // scan warmup; carry bound 0.7625^32 = 1.7e-4
#define TC 32           // scan chunk

typedef __attribute__((ext_vector_type(8))) short bf16x8;
typedef __attribute__((ext_vector_type(4))) float f32x4;

__device__ __forceinline__ ushort f2bf(float f) {
    union { float f; unsigned u; } v; v.f = f;
    unsigned r = v.u + 0x7fffu + ((v.u >> 16) & 1u);   // RNE
    return (ushort)(r >> 16);
}
__device__ __forceinline__ float bf2f(ushort u) {
    union { unsigned u; float f; } v; v.u = ((unsigned)u) << 16; return v.f;
}

// direct global->LDS async copy, 16B/lane (dest = wave-uniform base + lane*16)
__device__ __forceinline__ void gload16(const void* g, void* l) {
    using u32 = unsigned int;
    auto gp = (const __attribute__((address_space(1))) u32*)(uintptr_t)g;
    auto lp = (__attribute__((address_space(3))) u32*)(uintptr_t)l;
    __builtin_amdgcn_global_load_lds(gp, lp, 16, 0, 0);
}

// ---------------- phase-preserving RMS norm: h[BT,D,2] -> xnp (fragment-packed bf16)
// XCD-aligned: block v=bid&7 handles bt in [1024v, 1024v+1024).
__global__ __launch_bounds__(256)
void norm_kernel(const float* __restrict__ h, const float* __restrict__ g,
                 ushort* __restrict__ xnp)
{
    const int bt = (blockIdx.x & 7)*1024 + (blockIdx.x >> 3);
    const int d  = threadIdx.x;
    const float2 v = reinterpret_cast<const float2*>(h)[(size_t)bt*Dn + d];
    float sum = v.x*v.x + v.y*v.y;
    #pragma unroll
    for (int o = 32; o > 0; o >>= 1) sum += __shfl_down(sum, o);
    __shared__ float ws4[4];
    if ((threadIdx.x & 63) == 0) ws4[threadIdx.x >> 6] = sum;
    __syncthreads();
    const float tot = ws4[0] + ws4[1] + ws4[2] + ws4[3];
    const float rms = sqrtf(tot * (1.0f/Dn) + 1e-6f);
    const float scale = g[d] / rms;
    const int rowgrp = bt >> 4, rl = bt & 15;
    const int k1 = d, k2 = 256 + d;
    const size_t i1 = (((size_t)rowgrp*16 + (k1>>5))*64 + ((k1>>3)&3)*16 + rl)*8 + (k1&7);
    const size_t i2 = (((size_t)rowgrp*16 + (k2>>5))*64 + ((k2>>3)&3)*16 + rl)*8 + (k2&7);
    xnp[i1] = f2bf(v.x * scale);
    xnp[i2] = f2bf(v.y * scale);
}

// ---------------- final norm, fp32 interleaved output (same XCD-aligned decode)
__global__ __launch_bounds__(256)
void out_norm_kernel(const float* __restrict__ h, const float* __restrict__ g,
                     float* __restrict__ out)
{
    const int bt = (blockIdx.x & 7)*1024 + (blockIdx.x >> 3);
    const int d  = threadIdx.x;
    const float2 v = reinterpret_cast<const float2*>(h)[(size_t)bt*Dn + d];
    float sum = v.x*v.x + v.y*v.y;
    #pragma unroll
    for (int o = 32; o > 0; o >>= 1) sum += __shfl_down(sum, o);
    __shared__ float ws4[4];
    if ((threadIdx.x & 63) == 0) ws4[threadIdx.x >> 6] = sum;
    __syncthreads();
    const float tot = ws4[0] + ws4[1] + ws4[2] + ws4[3];
    const float rms = sqrtf(tot * (1.0f/Dn) + 1e-6f);
    const float scale = g[d] / rms;
    float2 o; o.x = v.x * scale; o.y = v.y * scale;
    reinterpret_cast<float2*>(out)[(size_t)bt*Dn + d] = o;
}

// ======== GEMM1: zb[8192,1536] = xn @ W1^T  (R12 verbatim — fastest measured variant)
// Block: 48-col panel (48KB LDS, full K=512) x 512 rows; 8 waves x (64 rows x 48 cols).
// AS 8-deep global prefetch + BS 4-deep LDS prefetch, 16 iters, 12 MFMA/iter.
// Grid 512 = exactly 2 blocks/CU; XCD v owns rsplits {2v, 2v+1}.
__global__ __launch_bounds__(512, 2)
void gemm1_kernel(const ushort* __restrict__ xnp, const ushort* __restrict__ W1f,
                  ushort* __restrict__ zb, const float* __restrict__ bias)
{
    __shared__ ushort Blds[24576];   // 48 KB: [n(3)][ks(16)][lane(64)][e(8)]
    const int tid = threadIdx.x, lane = tid & 63, wid = tid >> 6;
    const int xcd = blockIdx.x & 7, j = blockIdx.x >> 3;   // j 0..63
    const int rsplit = xcd*2 + (j & 1);   // 0..15 (512-row splits)
    const int panel  = j >> 1;            // 0..31 (48-col panels)

    // stage B panel: 48 KB contiguous (W1f fragment-packed, colgrp-major)
    const char* src = (const char*)(W1f + (size_t)panel*24576);
    #pragma unroll
    for (int r = 0; r < 6; ++r)
        gload16(src + r*8192 + tid*16, (char*)Blds + r*8192 + wid*1024);
    asm volatile("s_waitcnt vmcnt(0)" ::: "memory");
    __syncthreads();

    const int rgbase = rsplit*32 + wid*4;
    const ushort* pa = xnp + (size_t)rgbase*16*512 + lane*8;

    f32x4 acc[4][3] = {};
    bf16x8 AS[8][4], BS[4][3];

#define LDA1(s, ks) { _Pragma("unroll") for (int m = 0; m < 4; ++m) \
    AS[s][m] = *(const bf16x8*)(pa + ((size_t)m*16 + (ks))*512); }
#define LDB1(s, ks) { _Pragma("unroll") for (int n = 0; n < 3; ++n) \
    BS[s][n] = *(const bf16x8*)(Blds + ((n)*16 + (ks))*512 + lane*8); }

    LDA1(0,0); LDA1(1,1); LDA1(2,2); LDA1(3,3);
    LDA1(4,4); LDA1(5,5); LDA1(6,6); LDA1(7,7);
    LDB1(0,0); LDB1(1,1); LDB1(2,2); LDB1(3,3);
    __builtin_amdgcn_sched_barrier(0);
    #pragma unroll
    for (int ks = 0; ks < 16; ++ks) {
        #pragma unroll
        for (int n = 0; n < 3; ++n)
            #pragma unroll
            for (int m = 0; m < 4; ++m)
                acc[m][n] = __builtin_amdgcn_mfma_f32_16x16x32_bf16(AS[ks & 7][m], BS[ks & 3][n], acc[m][n], 0, 0, 0);
        if (ks + 8 < 16) LDA1((ks & 7), ks + 8);
        if (ks + 4 < 16) LDB1((ks & 3), ks + 4);
        __builtin_amdgcn_sched_barrier(0);
    }
#undef LDA1
#undef LDB1

    const int rl = lane & 15, rbase = (lane >> 4)*4;
    #pragma unroll
    for (int m = 0; m < 4; ++m) {
        #pragma unroll
        for (int n = 0; n < 3; ++n) {
            const int gcol = panel*48 + n*16 + rl;
            const float badd = bias[gcol];
            const bool sg = (gcol >= 1024);
            #pragma unroll
            for (int r = 0; r < 4; ++r) {
                const int grow = rsplit*512 + wid*64 + m*16 + rbase + r;
                float v = acc[m][n][r] + badd;
                if (sg) v = 1.0f/(1.0f + __expf(-v));
                zb[(size_t)grow*ZW + gcol] = f2bf(v);
            }
        }
    }
}

// ======== scan (warmup, 1 pass): zb -> hsp fragment-packed (XCD-aligned, R18 verbatim)
__global__ __launch_bounds__(256)
void scan_kernel(const ushort* __restrict__ zb, const float* __restrict__ theta,
                 const float* __restrict__ dp, const float* __restrict__ h0,
                 ushort* __restrict__ hsp)
{
    const int v = blockIdx.x & 7, i = blockIdx.x >> 3;
    const int b = v >> 1;
    const int c = (v & 1)*32 + i;
    const int s = blockIdx.z*256 + threadIdx.x;
    const int t0 = c*TC;
    const float th = theta[s], ct = cosf(th), st = sinf(th);
    const float damp = 0.5f + 0.5f/(1.0f + __expf(-dp[s]));
    const int wstart = (t0 >= WARM) ? (t0 - WARM) : 0;
    float hr = 0.f, hi = 0.f;
    if (wstart == 0) {
        hr = h0[((size_t)b*Sn + s)*2];
        hi = h0[((size_t)b*Sn + s)*2 + 1];
    }
    const ushort* row = zb + (size_t)(b*Tn + wstart)*ZW;
    for (int t = wstart; t < t0; ++t, row += ZW) {
        const float br = bf2f(row[s]), bi = bf2f(row[512+s]), g = bf2f(row[1024+s]);
        const float mm = (1.0f - g)*damp;
        const float mc = mm*ct, ms = mm*st;
        const float rr = mc*hr - ms*hi, ri = ms*hr + mc*hi;
        hr = g*br + rr;  hi = g*bi + ri;
    }
    const int rgb = (b*Tn + t0) >> 4;
    const int kg16 = ((s >> 3) & 3)*16;
    const int e = s & 7;
    const int srow = (s >> 5)*512 + e;
    #pragma unroll
    for (int t = 0; t < TC; ++t, row += ZW) {
        const float br = bf2f(row[s]), bi = bf2f(row[512+s]), g = bf2f(row[1024+s]);
        const float mm = (1.0f - g)*damp;
        const float mc = mm*ct, ms = mm*st;
        const float rr = mc*hr - ms*hi, ri = ms*hr + mc*hi;
        hr = g*br + rr;  hi = g*bi + ri;
        const size_t ro = ((size_t)(rgb + (t >> 4))*32)*512 + srow + (kg16 + (t & 15))*8;
        hsp[ro]           = f2bf(hr);
        hsp[ro + 16*512]  = f2bf(hi);
    }
}

// ======== GEMM2 (B-panel in LDS, pinned reg pipeline): y = [hs|xn] @ W2^T (K=1536),
// interleaved (yr,yi) cols, fused residual h += 0.1*((1+yr)*y).  (R18 verbatim)
__global__ __launch_bounds__(512, 2)
void gemm2_kernel(const ushort* __restrict__ hsp, const ushort* __restrict__ xnp,
                  const ushort* __restrict__ W2f, float* __restrict__ h)
{
    __shared__ ushort Blds[49152];   // 96 KB: [n(2)][ks(48)][lane(64)][e(8)]
    const int tid = threadIdx.x, lane = tid & 63, wid = tid >> 6;
    const int xcd = blockIdx.x & 7, j = blockIdx.x >> 3;
    const int rsplit = xcd*2 + (j & 1);
    const int panel  = j >> 1;

    const char* src = (const char*)(W2f + (size_t)panel*49152);
    #pragma unroll
    for (int r = 0; r < 12; ++r)
        gload16(src + r*8192 + tid*16, (char*)Blds + r*8192 + wid*1024);
    asm volatile("s_waitcnt vmcnt(0)" ::: "memory");
    __syncthreads();

    const int rgbase = rsplit*32 + wid*4;
    const ushort* pa_h = hsp + (size_t)rgbase*32*512 + lane*8;
    const ushort* pa_x = xnp + (size_t)rgbase*16*512 + lane*8;

    f32x4 acc[4][2] = {};
    bf16x8 AS[8][4], BS[4][2];

#define LDA2(s, ks) { if ((ks) < 32) { \
    _Pragma("unroll") for (int m = 0; m < 4; ++m) \
        AS[s][m] = *(const bf16x8*)(pa_h + ((size_t)m*32 + (ks))*512); \
    } else { \
    _Pragma("unroll") for (int m = 0; m < 4; ++m) \
        AS[s][m] = *(const bf16x8*)(pa_x + ((size_t)m*16 + (ks) - 32)*512); } }
#define LDB2(s, ks) { _Pragma("unroll") for (int n = 0; n < 2; ++n) \
    BS[s][n] = *(const bf16x8*)(Blds + ((n)*48 + (ks))*512 + lane*8); }

    LDA2(0,0); LDA2(1,1); LDA2(2,2); LDA2(3,3);
    LDA2(4,4); LDA2(5,5); LDA2(6,6); LDA2(7,7);
    LDB2(0,0); LDB2(1,1); LDB2(2,2); LDB2(3,3);
    __builtin_amdgcn_sched_barrier(0);
    #pragma unroll
    for (int ks = 0; ks < 48; ++ks) {
        __builtin_amdgcn_s_setprio(1);
        #pragma unroll
        for (int n = 0; n < 2; ++n)
            #pragma unroll
            for (int m = 0; m < 4; ++m)
                acc[m][n] = __builtin_amdgcn_mfma_f32_16x16x32_bf16(AS[ks & 7][m], BS[ks & 3][n], acc[m][n], 0, 0, 0);
        __builtin_amdgcn_s_setprio(0);
        if (ks + 8 < 48) LDA2((ks & 7), ks + 8);
        if (ks + 4 < 48) LDB2((ks & 3), ks + 4);
        __builtin_amdgcn_sched_barrier(0);
    }
#undef LDA2
#undef LDB2

    const int rl = lane & 15, rbase = (lane >> 4)*4;
    #pragma unroll
    for (int m = 0; m < 4; ++m) {
        #pragma unroll
        for (int n = 0; n < 2; ++n) {
            const int gcol = panel*32 + n*16 + rl;   // parity(gcol)==parity(lane)
            #pragma unroll
            for (int r = 0; r < 4; ++r) {
                const int grow = rsplit*512 + wid*64 + m*16 + rbase + r;
                float v = acc[m][n][r];
                const float p = __shfl_xor(v, 1);
                const float yr = (gcol & 1) ? p : v;
                h[(size_t)grow*512 + gcol] += 0.1f*(yr*v + v);
            }
        }
    }
}

// ---------------- weight prep: W1f fragment-packed [colgrp(96)][ks(16)][lane][8]
__global__ __launch_bounds__(512)
void prep_w1(const float* __restrict__ Bwr, const float* __restrict__ Bwi,
             const float* __restrict__ Gw, ushort* __restrict__ W1f)
{
    const int l = blockIdx.y;
    const int bx = blockIdx.x;          // colgrp*16 + ks
    const int lane = threadIdx.x >> 3, e = threadIdx.x & 7;
    const int n = (bx >> 4)*16 + (lane & 15);
    const int k = (bx & 15)*32 + (lane >> 4)*8 + e;
    const float* bwr = Bwr + (size_t)l*Dn*Sn;
    const float* bwi = Bwi + (size_t)l*Dn*Sn;
    const float* gw  = Gw  + (size_t)l*2*Dn*Sn;
    float v;
    if (n < 512)        { const int s = n;      v = (k < 256) ? bwr[k*Sn + s] : -bwi[(k-256)*Sn + s]; }
    else if (n < 1024)  { const int s = n-512;  v = (k < 256) ? bwi[k*Sn + s] :  bwr[(k-256)*Sn + s]; }
    else                { const int s = n-1024; v = gw[(size_t)k*Sn + s]; }
    W1f[(size_t)l*1536*512 + (size_t)bx*512 + threadIdx.x] = f2bf(v);
}

// ---------------- weight prep: W2f fragment-packed [colgrp(32)][ks(48)][lane][8]
// K = [hs_r(512) | hs_i(512) | xr,xi(512)]; cols interleaved (yr,yi)
__global__ __launch_bounds__(512)
void prep_w2(const float* __restrict__ Cwr, const float* __restrict__ Cwi,
             const float* __restrict__ Dwr, const float* __restrict__ Dwi,
             ushort* __restrict__ W2f)
{
    const int l = blockIdx.y;
    const int bx = blockIdx.x;          // colgrp*48 + ks
    const int lane = threadIdx.x >> 3, e = threadIdx.x & 7;
    const int n = (bx / 48)*16 + (lane & 15);
    const int k = (bx % 48)*32 + (lane >> 4)*8 + e;
    const float* cwr = Cwr + (size_t)l*Sn*Dn;
    const float* cwi = Cwi + (size_t)l*Sn*Dn;
    const float* dwr = Dwr + (size_t)l*Dn*Dn;
    const float* dwi = Dwi + (size_t)l*Dn*Dn;
    const int d = n >> 1;
    const bool im = (n & 1);
    float v;
    if (k < 512)       v = im ? cwi[k*Dn + d]        :  cwr[k*Dn + d];
    else if (k < 1024) v = im ? cwr[(k-512)*Dn + d]  : -cwi[(k-512)*Dn + d];
    else if (k < 1280) v = im ? dwi[(k-1024)*Dn + d] :  dwr[(k-1024)*Dn + d];
    else               v = im ? dwr[(k-1280)*Dn + d] : -dwi[(k-1280)*Dn + d];
    W2f[(size_t)l*512*1536 + (size_t)bx*512 + threadIdx.x] = f2bf(v);
}

// ---------------- bias prep (1536 wide; gate bias in [1024,1536))
__global__ __launch_bounds__(256)
void prep_bias(const float* __restrict__ gb, float* __restrict__ biasf)
{
    const int l = blockIdx.y;
    const int n = blockIdx.x*256 + threadIdx.x;
    biasf[(size_t)l*1536 + n] = (n >= 1024) ? gb[(size_t)l*Sn + n - 1024] : 0.0f;
}

extern "C" void kernel_launch(void* const* d_in, const int* in_sizes, int n_in,
                              void* d_out, int out_size, void* d_ws, size_t ws_size,
                              hipStream_t stream)
{
    const float* x      = (const float*)d_in[0];
    const float* h0     = (const float*)d_in[1];
    const float* theta  = (const float*)d_in[2];
    const float* dp     = (const float*)d_in[3];
    const float* B_wr   = (const float*)d_in[4];
    const float* B_wi   = (const float*)d_in[5];
    const float* C_wr   = (const float*)d_in[6];
    const float* C_wi   = (const float*)d_in[7];
    const float* D_wr   = (const float*)d_in[8];
    const float* D_wi   = (const float*)d_in[9];
    const float* gate_w = (const float*)d_in[10];
    const float* gate_b = (const float*)d_in[11];
    const float* norm_g = (const float*)d_in[12];
    const float* out_g  = (const float*)d_in[13];
    float* out = (float*)d_out;

    char* w = (char*)d_ws;
    float*  h     = (float*)w;   w += (size_t)BT*512*4;         // 16 MB
    float*  biasf = (float*)w;   w += (size_t)8*1536*4;         // 48 KB
    ushort* zb    = (ushort*)w;  w += (size_t)BT*ZW*2;          // 24 MB
    ushort* xnp   = (ushort*)w;  w += (size_t)BT*512*2;         // 8 MB
    ushort* hsp   = (ushort*)w;  w += (size_t)BT*1024*2;        // 16 MB
    ushort* W1f   = (ushort*)w;  w += (size_t)Lnum*1536*512*2;  // 16 MB
    ushort* W2f   = (ushort*)w;  w += (size_t)Lnum*512*1536*2;  // 16 MB

    hipMemcpyAsync(h, x, sizeof(float)*(size_t)BT*Dn*2, hipMemcpyDeviceToDevice, stream);

    prep_w1<<<dim3(1536, Lnum), 512, 0, stream>>>(B_wr, B_wi, gate_w, W1f);
    prep_w2<<<dim3(1536, Lnum), 512, 0, stream>>>(C_wr, C_wi, D_wr, D_wi, W2f);
    prep_bias<<<dim3(6, Lnum), 256, 0, stream>>>(gate_b, biasf);

    for (int l = 0; l < Lnum; ++l) {
        norm_kernel<<<BT, 256, 0, stream>>>(h, norm_g + (size_t)l*Dn, xnp);

        gemm1_kernel<<<512, 512, 0, stream>>>(xnp, W1f + (size_t)l*1536*512, zb,
                                              biasf + (size_t)l*1536);

        scan_kernel<<<dim3(256, 1, 2), 256, 0, stream>>>(zb, theta + (size_t)l*Sn,
                                                         dp + (size_t)l*Sn,
                                                         h0 + (size_t)l*Bn*Sn*2, hsp);

        gemm2_kernel<<<256, 512, 0, stream>>>(hsp, xnp, W2f + (size_t)l*512*1536, h);
    }

    out_norm_kernel<<<BT, 256, 0, stream>>>(h, out_g, out);
}

// Round 22
// 556.158 us; speedup vs baseline: 1.3904x; 1.0728x over previous
//
#include <hip/hip_runtime.h>
#include <math.h>

#define Lnum 8
#define Bn 4
#define Tn 2048
#define Dn 256
#define Sn 512
#define BT (Bn*Tn)      // 8192
#define ZW 1536         // zb row: [bx_r(512) | bx_i(512) | gate(512)]
#define WARM 24         // scan warmup; carry bound 0.7625^24 = 1.5e-3
#define TC 32           // scan chunk

typedef __attribute__((ext_vector_type(8))) short bf16x8;
typedef __attribute__((ext_vector_type(4))) float f32x4;

__device__ __forceinline__ ushort f2bf(float f) {
    union { float f; unsigned u; } v; v.f = f;
    unsigned r = v.u + 0x7fffu + ((v.u >> 16) & 1u);   // RNE
    return (ushort)(r >> 16);
}
__device__ __forceinline__ float bf2f(ushort u) {
    union { unsigned u; float f; } v; v.u = ((unsigned)u) << 16; return v.f;
}

// direct global->LDS async copy, 16B/lane (dest = wave-uniform base + lane*16)
__device__ __forceinline__ void gload16(const void* g, void* l) {
    using u32 = unsigned int;
    auto gp = (const __attribute__((address_space(1))) u32*)(uintptr_t)g;
    auto lp = (__attribute__((address_space(3))) u32*)(uintptr_t)l;
    __builtin_amdgcn_global_load_lds(gp, lp, 16, 0, 0);
}

// ---------------- phase-preserving RMS norm: src[BT,D,2] -> xnp (fragment-packed bf16)
// XCD-aligned: block v=bid&7 handles bt in [1024v, 1024v+1024).
__global__ __launch_bounds__(256)
void norm_kernel(const float* __restrict__ src, const float* __restrict__ g,
                 ushort* __restrict__ xnp)
{
    const int bt = (blockIdx.x & 7)*1024 + (blockIdx.x >> 3);
    const int d  = threadIdx.x;
    const float2 v = reinterpret_cast<const float2*>(src)[(size_t)bt*Dn + d];
    float sum = v.x*v.x + v.y*v.y;
    #pragma unroll
    for (int o = 32; o > 0; o >>= 1) sum += __shfl_down(sum, o);
    __shared__ float ws4[4];
    if ((threadIdx.x & 63) == 0) ws4[threadIdx.x >> 6] = sum;
    __syncthreads();
    const float tot = ws4[0] + ws4[1] + ws4[2] + ws4[3];
    const float rms = sqrtf(tot * (1.0f/Dn) + 1e-6f);
    const float scale = g[d] / rms;
    const int rowgrp = bt >> 4, rl = bt & 15;
    const int k1 = d, k2 = 256 + d;
    const size_t i1 = (((size_t)rowgrp*16 + (k1>>5))*64 + ((k1>>3)&3)*16 + rl)*8 + (k1&7);
    const size_t i2 = (((size_t)rowgrp*16 + (k2>>5))*64 + ((k2>>3)&3)*16 + rl)*8 + (k2&7);
    xnp[i1] = f2bf(v.x * scale);
    xnp[i2] = f2bf(v.y * scale);
}

// ---------------- final norm, fp32 interleaved output (same XCD-aligned decode)
__global__ __launch_bounds__(256)
void out_norm_kernel(const float* __restrict__ h, const float* __restrict__ g,
                     float* __restrict__ out)
{
    const int bt = (blockIdx.x & 7)*1024 + (blockIdx.x >> 3);
    const int d  = threadIdx.x;
    const float2 v = reinterpret_cast<const float2*>(h)[(size_t)bt*Dn + d];
    float sum = v.x*v.x + v.y*v.y;
    #pragma unroll
    for (int o = 32; o > 0; o >>= 1) sum += __shfl_down(sum, o);
    __shared__ float ws4[4];
    if ((threadIdx.x & 63) == 0) ws4[threadIdx.x >> 6] = sum;
    __syncthreads();
    const float tot = ws4[0] + ws4[1] + ws4[2] + ws4[3];
    const float rms = sqrtf(tot * (1.0f/Dn) + 1e-6f);
    const float scale = g[d] / rms;
    float2 o; o.x = v.x * scale; o.y = v.y * scale;
    reinterpret_cast<float2*>(out)[(size_t)bt*Dn + d] = o;
}

// ======== GEMM1: zb[8192,1536] = xn @ W1^T — R19 cadence version (96-col panel).
// Block: 96-col panel (96KB LDS, full K=512) x 512 rows; 8 waves x (64 rows x 96 cols).
// 48 iterations of (ks, colpair g). Grid 256 = 1 block/CU; XCD v owns rsplits {2v,2v+1}.
__global__ __launch_bounds__(512, 2)
void gemm1_kernel(const ushort* __restrict__ xnp, const ushort* __restrict__ W1f,
                  ushort* __restrict__ zb, const float* __restrict__ bias)
{
    __shared__ ushort Blds[49152];   // 96 KB: [n(6)][ks(16)][lane(64)][e(8)]
    const int tid = threadIdx.x, lane = tid & 63, wid = tid >> 6;
    const int xcd = blockIdx.x & 7, j0 = blockIdx.x >> 3;   // j0 0..31
    const int rsplit = xcd*2 + (j0 & 1);   // 0..15 (512-row splits)
    const int panel  = j0 >> 1;            // 0..15 (96-col panels)

    const char* src = (const char*)(W1f + (size_t)panel*49152);
    #pragma unroll
    for (int r = 0; r < 12; ++r)
        gload16(src + r*8192 + tid*16, (char*)Blds + r*8192 + wid*1024);
    asm volatile("s_waitcnt vmcnt(0)" ::: "memory");
    __syncthreads();

    const int rgbase = rsplit*32 + wid*4;
    const ushort* pa = xnp + (size_t)rgbase*16*512 + lane*8;

    f32x4 acc[4][6] = {};
    bf16x8 AS[4][4], BS[4][2];

#define LDA1(s, ks) { _Pragma("unroll") for (int m = 0; m < 4; ++m) \
    AS[s][m] = *(const bf16x8*)(pa + ((size_t)m*16 + (ks))*512); }
#define LDB1(s, jj) { _Pragma("unroll") for (int n2 = 0; n2 < 2; ++n2) \
    BS[s][n2] = *(const bf16x8*)(Blds + ((((jj)%3)*2 + n2)*16 + ((jj)/3))*512 + lane*8); }

    LDA1(0,0); LDA1(1,1); LDA1(2,2); LDA1(3,3);
    LDB1(0,0); LDB1(1,1); LDB1(2,2); LDB1(3,3);
    __builtin_amdgcn_sched_barrier(0);
    #pragma unroll
    for (int j = 0; j < 48; ++j) {
        const int ks = j/3, g = j%3;
        __builtin_amdgcn_s_setprio(1);
        #pragma unroll
        for (int n2 = 0; n2 < 2; ++n2)
            #pragma unroll
            for (int m = 0; m < 4; ++m)
                acc[m][g*2+n2] = __builtin_amdgcn_mfma_f32_16x16x32_bf16(AS[ks & 3][m], BS[j & 3][n2], acc[m][g*2+n2], 0, 0, 0);
        __builtin_amdgcn_s_setprio(0);
        if (j + 4 < 48) LDB1((j & 3), j + 4);
        if (g == 2 && ks + 4 < 16) LDA1((ks & 3), ks + 4);
        __builtin_amdgcn_sched_barrier(0);
    }
#undef LDA1
#undef LDB1

    const int rl = lane & 15, rbase = (lane >> 4)*4;
    #pragma unroll
    for (int m = 0; m < 4; ++m) {
        #pragma unroll
        for (int n = 0; n < 6; ++n) {
            const int gcol = panel*96 + n*16 + rl;
            const float badd = bias[gcol];
            const bool sg = (gcol >= 1024);
            #pragma unroll
            for (int r = 0; r < 4; ++r) {
                const int grow = rsplit*512 + wid*64 + m*16 + rbase + r;
                float v = acc[m][n][r] + badd;
                if (sg) v = 1.0f/(1.0f + __expf(-v));
                zb[(size_t)grow*ZW + gcol] = f2bf(v);
            }
        }
    }
}

// ======== scan (warmup, 1 pass): zb -> hsp fragment-packed (XCD-aligned)
__global__ __launch_bounds__(256)
void scan_kernel(const ushort* __restrict__ zb, const float* __restrict__ theta,
                 const float* __restrict__ dp, const float* __restrict__ h0,
                 ushort* __restrict__ hsp)
{
    const int v = blockIdx.x & 7, i = blockIdx.x >> 3;
    const int b = v >> 1;
    const int c = (v & 1)*32 + i;
    const int s = blockIdx.z*256 + threadIdx.x;
    const int t0 = c*TC;
    const float th = theta[s], ct = cosf(th), st = sinf(th);
    const float damp = 0.5f + 0.5f/(1.0f + __expf(-dp[s]));
    const int wstart = (t0 >= WARM) ? (t0 - WARM) : 0;
    float hr = 0.f, hi = 0.f;
    if (wstart == 0) {
        hr = h0[((size_t)b*Sn + s)*2];
        hi = h0[((size_t)b*Sn + s)*2 + 1];
    }
    const ushort* row = zb + (size_t)(b*Tn + wstart)*ZW;
    for (int t = wstart; t < t0; ++t, row += ZW) {
        const float br = bf2f(row[s]), bi = bf2f(row[512+s]), g = bf2f(row[1024+s]);
        const float mm = (1.0f - g)*damp;
        const float mc = mm*ct, ms = mm*st;
        const float rr = mc*hr - ms*hi, ri = ms*hr + mc*hi;
        hr = g*br + rr;  hi = g*bi + ri;
    }
    const int rgb = (b*Tn + t0) >> 4;
    const int kg16 = ((s >> 3) & 3)*16;
    const int e = s & 7;
    const int srow = (s >> 5)*512 + e;
    #pragma unroll
    for (int t = 0; t < TC; ++t, row += ZW) {
        const float br = bf2f(row[s]), bi = bf2f(row[512+s]), g = bf2f(row[1024+s]);
        const float mm = (1.0f - g)*damp;
        const float mc = mm*ct, ms = mm*st;
        const float rr = mc*hr - ms*hi, ri = ms*hr + mc*hi;
        hr = g*br + rr;  hi = g*bi + ri;
        const size_t ro = ((size_t)(rgb + (t >> 4))*32)*512 + srow + (kg16 + (t & 15))*8;
        hsp[ro]           = f2bf(hr);
        hsp[ro + 16*512]  = f2bf(hi);
    }
}

// ======== GEMM2 (B-panel in LDS, pinned reg pipeline): y = [hs|xn] @ W2^T (K=1536),
// interleaved (yr,yi) cols, fused residual h = hsrc + 0.1*((1+yr)*y).
// hsrc = x (layer 0, identical layout) or h; removes the initial h<-x memcpy.
__global__ __launch_bounds__(512, 2)
void gemm2_kernel(const ushort* __restrict__ hsp, const ushort* __restrict__ xnp,
                  const ushort* __restrict__ W2f, const float* __restrict__ hsrc,
                  float* __restrict__ h)
{
    __shared__ ushort Blds[49152];   // 96 KB: [n(2)][ks(48)][lane(64)][e(8)]
    const int tid = threadIdx.x, lane = tid & 63, wid = tid >> 6;
    const int xcd = blockIdx.x & 7, j = blockIdx.x >> 3;
    const int rsplit = xcd*2 + (j & 1);
    const int panel  = j >> 1;

    const char* src = (const char*)(W2f + (size_t)panel*49152);
    #pragma unroll
    for (int r = 0; r < 12; ++r)
        gload16(src + r*8192 + tid*16, (char*)Blds + r*8192 + wid*1024);
    asm volatile("s_waitcnt vmcnt(0)" ::: "memory");
    __syncthreads();

    const int rgbase = rsplit*32 + wid*4;
    const ushort* pa_h = hsp + (size_t)rgbase*32*512 + lane*8;
    const ushort* pa_x = xnp + (size_t)rgbase*16*512 + lane*8;

    f32x4 acc[4][2] = {};
    bf16x8 AS[8][4], BS[4][2];

#define LDA2(s, ks) { if ((ks) < 32) { \
    _Pragma("unroll") for (int m = 0; m < 4; ++m) \
        AS[s][m] = *(const bf16x8*)(pa_h + ((size_t)m*32 + (ks))*512); \
    } else { \
    _Pragma("unroll") for (int m = 0; m < 4; ++m) \
        AS[s][m] = *(const bf16x8*)(pa_x + ((size_t)m*16 + (ks) - 32)*512); } }
#define LDB2(s, ks) { _Pragma("unroll") for (int n = 0; n < 2; ++n) \
    BS[s][n] = *(const bf16x8*)(Blds + ((n)*48 + (ks))*512 + lane*8); }

    LDA2(0,0); LDA2(1,1); LDA2(2,2); LDA2(3,3);
    LDA2(4,4); LDA2(5,5); LDA2(6,6); LDA2(7,7);
    LDB2(0,0); LDB2(1,1); LDB2(2,2); LDB2(3,3);
    __builtin_amdgcn_sched_barrier(0);
    #pragma unroll
    for (int ks = 0; ks < 48; ++ks) {
        __builtin_amdgcn_s_setprio(1);
        #pragma unroll
        for (int n = 0; n < 2; ++n)
            #pragma unroll
            for (int m = 0; m < 4; ++m)
                acc[m][n] = __builtin_amdgcn_mfma_f32_16x16x32_bf16(AS[ks & 7][m], BS[ks & 3][n], acc[m][n], 0, 0, 0);
        __builtin_amdgcn_s_setprio(0);
        if (ks + 8 < 48) LDA2((ks & 7), ks + 8);
        if (ks + 4 < 48) LDB2((ks & 3), ks + 4);
        __builtin_amdgcn_sched_barrier(0);
    }
#undef LDA2
#undef LDB2

    const int rl = lane & 15, rbase = (lane >> 4)*4;
    #pragma unroll
    for (int m = 0; m < 4; ++m) {
        #pragma unroll
        for (int n = 0; n < 2; ++n) {
            const int gcol = panel*32 + n*16 + rl;   // parity(gcol)==parity(lane)
            #pragma unroll
            for (int r = 0; r < 4; ++r) {
                const int grow = rsplit*512 + wid*64 + m*16 + rbase + r;
                float v = acc[m][n][r];
                const float p = __shfl_xor(v, 1);
                const float yr = (gcol & 1) ? p : v;
                const size_t idx = (size_t)grow*512 + gcol;
                h[idx] = hsrc[idx] + 0.1f*(yr*v + v);
            }
        }
    }
}

// ---------------- weight prep: W1f fragment-packed [colgrp(96)][ks(16)][lane][8]
__global__ __launch_bounds__(512)
void prep_w1(const float* __restrict__ Bwr, const float* __restrict__ Bwi,
             const float* __restrict__ Gw, ushort* __restrict__ W1f)
{
    const int l = blockIdx.y;
    const int bx = blockIdx.x;          // colgrp*16 + ks
    const int lane = threadIdx.x >> 3, e = threadIdx.x & 7;
    const int n = (bx >> 4)*16 + (lane & 15);
    const int k = (bx & 15)*32 + (lane >> 4)*8 + e;
    const float* bwr = Bwr + (size_t)l*Dn*Sn;
    const float* bwi = Bwi + (size_t)l*Dn*Sn;
    const float* gw  = Gw  + (size_t)l*2*Dn*Sn;
    float v;
    if (n < 512)        { const int s = n;      v = (k < 256) ? bwr[k*Sn + s] : -bwi[(k-256)*Sn + s]; }
    else if (n < 1024)  { const int s = n-512;  v = (k < 256) ? bwi[k*Sn + s] :  bwr[(k-256)*Sn + s]; }
    else                { const int s = n-1024; v = gw[(size_t)k*Sn + s]; }
    W1f[(size_t)l*1536*512 + (size_t)bx*512 + threadIdx.x] = f2bf(v);
}

// ---------------- weight prep: W2f fragment-packed [colgrp(32)][ks(48)][lane][8]
// K = [hs_r(512) | hs_i(512) | xr,xi(512)]; cols interleaved (yr,yi)
__global__ __launch_bounds__(512)
void prep_w2(const float* __restrict__ Cwr, const float* __restrict__ Cwi,
             const float* __restrict__ Dwr, const float* __restrict__ Dwi,
             ushort* __restrict__ W2f)
{
    const int l = blockIdx.y;
    const int bx = blockIdx.x;          // colgrp*48 + ks
    const int lane = threadIdx.x >> 3, e = threadIdx.x & 7;
    const int n = (bx / 48)*16 + (lane & 15);
    const int k = (bx % 48)*32 + (lane >> 4)*8 + e;
    const float* cwr = Cwr + (size_t)l*Sn*Dn;
    const float* cwi = Cwi + (size_t)l*Sn*Dn;
    const float* dwr = Dwr + (size_t)l*Dn*Dn;
    const float* dwi = Dwi + (size_t)l*Dn*Dn;
    const int d = n >> 1;
    const bool im = (n & 1);
    float v;
    if (k < 512)       v = im ? cwi[k*Dn + d]        :  cwr[k*Dn + d];
    else if (k < 1024) v = im ? cwr[(k-512)*Dn + d]  : -cwi[(k-512)*Dn + d];
    else if (k < 1280) v = im ? dwi[(k-1024)*Dn + d] :  dwr[(k-1024)*Dn + d];
    else               v = im ? dwr[(k-1280)*Dn + d] : -dwi[(k-1280)*Dn + d];
    W2f[(size_t)l*512*1536 + (size_t)bx*512 + threadIdx.x] = f2bf(v);
}

// ---------------- bias prep (1536 wide; gate bias in [1024,1536))
__global__ __launch_bounds__(256)
void prep_bias(const float* __restrict__ gb, float* __restrict__ biasf)
{
    const int l = blockIdx.y;
    const int n = blockIdx.x*256 + threadIdx.x;
    biasf[(size_t)l*1536 + n] = (n >= 1024) ? gb[(size_t)l*Sn + n - 1024] : 0.0f;
}

extern "C" void kernel_launch(void* const* d_in, const int* in_sizes, int n_in,
                              void* d_out, int out_size, void* d_ws, size_t ws_size,
                              hipStream_t stream)
{
    const float* x      = (const float*)d_in[0];
    const float* h0     = (const float*)d_in[1];
    const float* theta  = (const float*)d_in[2];
    const float* dp     = (const float*)d_in[3];
    const float* B_wr   = (const float*)d_in[4];
    const float* B_wi   = (const float*)d_in[5];
    const float* C_wr   = (const float*)d_in[6];
    const float* C_wi   = (const float*)d_in[7];
    const float* D_wr   = (const float*)d_in[8];
    const float* D_wi   = (const float*)d_in[9];
    const float* gate_w = (const float*)d_in[10];
    const float* gate_b = (const float*)d_in[11];
    const float* norm_g = (const float*)d_in[12];
    const float* out_g  = (const float*)d_in[13];
    float* out = (float*)d_out;

    char* w = (char*)d_ws;
    float*  h     = (float*)w;   w += (size_t)BT*512*4;         // 16 MB
    float*  biasf = (float*)w;   w += (size_t)8*1536*4;         // 48 KB
    ushort* zb    = (ushort*)w;  w += (size_t)BT*ZW*2;          // 24 MB
    ushort* xnp   = (ushort*)w;  w += (size_t)BT*512*2;         // 8 MB
    ushort* hsp   = (ushort*)w;  w += (size_t)BT*1024*2;        // 16 MB
    ushort* W1f   = (ushort*)w;  w += (size_t)Lnum*1536*512*2;  // 16 MB
    ushort* W2f   = (ushort*)w;  w += (size_t)Lnum*512*1536*2;  // 16 MB

    prep_w1<<<dim3(1536, Lnum), 512, 0, stream>>>(B_wr, B_wi, gate_w, W1f);
    prep_w2<<<dim3(1536, Lnum), 512, 0, stream>>>(C_wr, C_wi, D_wr, D_wi, W2f);
    prep_bias<<<dim3(6, Lnum), 256, 0, stream>>>(gate_b, biasf);

    for (int l = 0; l < Lnum; ++l) {
        const float* hin = (l == 0) ? x : h;   // x and h share the same layout

        norm_kernel<<<BT, 256, 0, stream>>>(hin, norm_g + (size_t)l*Dn, xnp);

        gemm1_kernel<<<256, 512, 0, stream>>>(xnp, W1f + (size_t)l*1536*512, zb,
                                              biasf + (size_t)l*1536);

        scan_kernel<<<dim3(256, 1, 2), 256, 0, stream>>>(zb, theta + (size_t)l*Sn,
                                                         dp + (size_t)l*Sn,
                                                         h0 + (size_t)l*Bn*Sn*2, hsp);

        gemm2_kernel<<<256, 512, 0, stream>>>(hsp, xnp, W2f + (size_t)l*512*1536,
                                              hin, h);
    }

    out_norm_kernel<<<BT, 256, 0, stream>>>(h, out_g, out);
}